// Round 5
// baseline (207.671 us; speedup 1.0000x reference)
//
#include <hip/hip_runtime.h>

// B=8,H=8,S=1024,D=64 fp32 attention, raw-exp softmax, multiplicative key mask.
// Outputs: context[64,1024,64] then scores[64,1024,1024], both fp32.
// R5: single-pass, 16 q-rows/block (32 KB E-tile, 4 blocks/CU), full K/V/mask
// prefetch, nt contiguous score stores. Goal: overlap compute & store phases.

typedef float    f32x4 __attribute__((ext_vector_type(4)));
typedef _Float16 f16x8 __attribute__((ext_vector_type(8)));
typedef _Float16 f16x4 __attribute__((ext_vector_type(4)));

#define MFMA32(A, B, C) __builtin_amdgcn_mfma_f32_16x16x32_f16((A), (B), (C), 0, 0, 0)
#define MFMA16(A, B, C) __builtin_amdgcn_mfma_f32_16x16x16f16((A), (B), (C), 0, 0, 0)

#define BHN 64
#define SEQ 1024
#define DIM 64

__device__ inline f16x8 cvt8(f32x4 a, f32x4 b) {
    f16x8 r;
    r[0] = (_Float16)a[0]; r[1] = (_Float16)a[1]; r[2] = (_Float16)a[2]; r[3] = (_Float16)a[3];
    r[4] = (_Float16)b[0]; r[5] = (_Float16)b[1]; r[6] = (_Float16)b[2]; r[7] = (_Float16)b[3];
    return r;
}

// Pre-pass: K -> f16 same layout; V -> f16 transposed per (b,h): VT[bh][d][key].
__global__ __launch_bounds__(256)
void cvt_kv(const float* __restrict__ K, const float* __restrict__ V,
            _Float16* __restrict__ Kh, _Float16* __restrict__ VT)
{
    __shared__ _Float16 tile[128 * 65];
    const int bh = blockIdx.x >> 3;
    const int kc = blockIdx.x & 7;
    const int t  = threadIdx.x;
    const size_t base = ((size_t)bh * SEQ + (size_t)kc * 128) * DIM;

    for (int it = 0; it < 8; ++it) {
        int idx = it * 256 + t;
        int key = idx >> 4;
        int c4  = idx & 15;
        f32x4 kv = *(const f32x4*)(K + base + key * DIM + c4 * 4);
        f32x4 vv = *(const f32x4*)(V + base + key * DIM + c4 * 4);
        f16x4 kh4;
        kh4[0] = (_Float16)kv[0]; kh4[1] = (_Float16)kv[1];
        kh4[2] = (_Float16)kv[2]; kh4[3] = (_Float16)kv[3];
        *(f16x4*)(Kh + base + key * DIM + c4 * 4) = kh4;
        tile[key * 65 + c4 * 4 + 0] = (_Float16)vv[0];
        tile[key * 65 + c4 * 4 + 1] = (_Float16)vv[1];
        tile[key * 65 + c4 * 4 + 2] = (_Float16)vv[2];
        tile[key * 65 + c4 * 4 + 3] = (_Float16)vv[3];
    }
    __syncthreads();
    for (int it = 0; it < 4; ++it) {
        int idx = it * 256 + t;
        int dd = idx >> 4;
        int kg = idx & 15;
        f16x8 o;
        #pragma unroll
        for (int j = 0; j < 8; ++j) o[j] = tile[(kg * 8 + j) * 65 + dd];
        *(f16x8*)(VT + ((size_t)bh * DIM + dd) * SEQ + (size_t)kc * 128 + kg * 8) = o;
    }
}

// Main kernel. 4096 blocks x 256 thr (4 waves). Block = 16 q-rows, all 1024 keys.
// Wave w owns key quarter [w*256, w*256+256).
// Swapped QK^T: acc = mfma(A=K, B=Q) -> lane: qrow = lane&15, key = (lane>>4)*4+i.
// E=exp(s)*mask staged f16 in 32 KB LDS tile (XOR-swizzled 8-B granules).
template <bool PRECONV>
__global__ __launch_bounds__(256, 4)
void attn_main(const float* __restrict__ Q, const float* __restrict__ mask,
               const _Float16* __restrict__ Kh, const _Float16* __restrict__ VT,
               float* __restrict__ ctx, float* __restrict__ scores)
{
    __shared__ __align__(16) _Float16 Et[16 * 1024];   // 32 KB
    __shared__ float inv_lds[16];

    const int bid = blockIdx.x;
    const int wg  = ((bid & 7) << 9) | (bid >> 3);  // XCD-bijective (4096 % 8 == 0)
    const int bh  = wg >> 6;
    const int qb  = wg & 63;
    const int b   = bh >> 3;
    const int w    = threadIdx.x >> 6;   // key quarter
    const int lane = threadIdx.x & 63;
    const int col  = lane & 15;
    const int g    = lane >> 4;
    const int q0   = qb * 16;
    const int kb   = w * 256;
    const float scale = 0.125f;
    char* EtB = (char*)Et;

    // ---- Q fragments: qf[f] : Q[q0+col][f*32 + g*8 .. +7]
    f16x8 qf[2];
    {
        const float* p = Q + ((size_t)bh * SEQ + q0 + col) * DIM + g * 8;
        qf[0] = cvt8(*(const f32x4*)p,        *(const f32x4*)(p + 4));
        qf[1] = cvt8(*(const f32x4*)(p + 32), *(const f32x4*)(p + 36));
    }
    const float* mb = mask + (size_t)b * SEQ + kb;
    const _Float16* kbase = Kh + ((size_t)bh * SEQ + kb + col) * DIM + g * 8;
    const _Float16* vtb   = VT + (size_t)bh * DIM * SEQ + kb + col * SEQ + g * 4;

    f32x4 cacc[4];
    #pragma unroll
    for (int dt = 0; dt < 4; ++dt) cacc[dt] = (f32x4){0.f, 0.f, 0.f, 0.f};

    // ---- single pass over this wave's 16 k-tiles, one-ahead prefetch
    f16x8 k0, k1;
    f32x4 m4;
    f16x4 vt[4];
    k0 = *(const f16x8*)(kbase);
    k1 = *(const f16x8*)(kbase + 32);
    m4 = *(const f32x4*)(mb + g * 4);
    #pragma unroll
    for (int dt = 0; dt < 4; ++dt) vt[dt] = *(const f16x4*)(vtb + (size_t)dt * 16 * SEQ);

    for (int kt = 0; kt < 16; ++kt) {
        const int ktn = (kt + 1) & 15;
        f16x8 n0 = *(const f16x8*)(kbase + (size_t)ktn * 16 * DIM);
        f16x8 n1 = *(const f16x8*)(kbase + (size_t)ktn * 16 * DIM + 32);
        f32x4 nm = *(const f32x4*)(mb + ktn * 16 + g * 4);
        f16x4 nvt[4];
        #pragma unroll
        for (int dt = 0; dt < 4; ++dt)
            nvt[dt] = *(const f16x4*)(vtb + (size_t)dt * 16 * SEQ + ktn * 16);

        f32x4 acc = {0.f, 0.f, 0.f, 0.f};
        acc = MFMA32(k0, qf[0], acc);
        acc = MFMA32(k1, qf[1], acc);
        f16x4 pf;
        pf[0] = (_Float16)(__expf(acc[0] * scale) * m4[0]);
        pf[1] = (_Float16)(__expf(acc[1] * scale) * m4[1]);
        pf[2] = (_Float16)(__expf(acc[2] * scale) * m4[2]);
        pf[3] = (_Float16)(__expf(acc[3] * scale) * m4[3]);
        const int kg = (w * 64 + kt * 4 + g) ^ ((col & 3) << 2);
        *(f16x4*)(EtB + col * 2048 + kg * 8) = pf;

        #pragma unroll
        for (int dt = 0; dt < 4; ++dt)
            cacc[dt] = MFMA16(vt[dt], pf, cacc[dt]);

        k0 = n0; k1 = n1; m4 = nm;
        #pragma unroll
        for (int dt = 0; dt < 4; ++dt) vt[dt] = nvt[dt];
    }

    __syncthreads();

    // ---- phase 3: wave w rows w*4..w*4+3. 4 independent reductions (ILP), then
    // full-row contiguous nt stores (4 x 1 KB per row).
    {
        const int r0 = w * 4;
        f16x4 ev[4][4];
        float ps[4];
        #pragma unroll
        for (int j = 0; j < 4; ++j) {
            const int r = r0 + j;
            float s0 = 0.f;
            #pragma unroll
            for (int q = 0; q < 4; ++q) {
                const int kg = (q * 64 + lane) ^ ((r & 3) << 2);
                ev[j][q] = *(const f16x4*)(EtB + r * 2048 + kg * 8);
                s0 += (float)ev[j][q][0] + (float)ev[j][q][1]
                    + (float)ev[j][q][2] + (float)ev[j][q][3];
            }
            ps[j] = s0;
        }
        #pragma unroll
        for (int off = 1; off < 64; off <<= 1) {
            #pragma unroll
            for (int j = 0; j < 4; ++j) ps[j] += __shfl_xor(ps[j], off, 64);
        }
        float* srow = scores + ((size_t)bh * SEQ + q0) * SEQ;
        #pragma unroll
        for (int j = 0; j < 4; ++j) {
            const int r = r0 + j;
            const float invr = 1.0f / (ps[j] + 1e-8f);
            if (lane == 0) inv_lds[r] = invr;
            float* dst = srow + (size_t)r * SEQ + lane * 4;
            #pragma unroll
            for (int q = 0; q < 4; ++q) {
                f32x4 o;
                o[0] = (float)ev[j][q][0] * invr;
                o[1] = (float)ev[j][q][1] * invr;
                o[2] = (float)ev[j][q][2] * invr;
                o[3] = (float)ev[j][q][3] * invr;
                __builtin_nontemporal_store(o, (f32x4*)(dst + q * 256));
            }
        }
    }

    __syncthreads();

    // ---- PV combine across waves (E-tile is dead; alias as float scratch)
    float* dumpf = (float*)Et;
    if (w != 0) {
        float* d = dumpf + (w - 1) * 1024;
        #pragma unroll
        for (int dt = 0; dt < 4; ++dt)
            #pragma unroll
            for (int i = 0; i < 4; ++i)
                d[(dt * 4 + i) * 64 + lane] = cacc[dt][i];
    }
    __syncthreads();
    if (w == 0) {
        const float invr = inv_lds[col];
        #pragma unroll
        for (int dt = 0; dt < 4; ++dt) {
            f32x4 r = cacc[dt];
            #pragma unroll
            for (int ww = 0; ww < 3; ++ww) {
                const float* d = dumpf + ww * 1024;
                #pragma unroll
                for (int i = 0; i < 4; ++i)
                    r[i] += d[(dt * 4 + i) * 64 + lane];
            }
            r[0] *= invr; r[1] *= invr; r[2] *= invr; r[3] *= invr;
            *(f32x4*)(ctx + ((size_t)bh * SEQ + q0 + col) * DIM + dt * 16 + g * 4) = r;
        }
    }
}

// Fallback path (no workspace): same structure, K/V converted on the fly.
__global__ __launch_bounds__(256, 4)
void attn_fallback(const float* __restrict__ Q, const float* __restrict__ K,
                   const float* __restrict__ V, const float* __restrict__ mask,
                   float* __restrict__ ctx, float* __restrict__ scores)
{
    __shared__ __align__(16) _Float16 Et[16 * 1024];
    __shared__ float inv_lds[16];

    const int bid = blockIdx.x;
    const int wg  = ((bid & 7) << 9) | (bid >> 3);
    const int bh  = wg >> 6;
    const int qb  = wg & 63;
    const int b   = bh >> 3;
    const int w    = threadIdx.x >> 6;
    const int lane = threadIdx.x & 63;
    const int col  = lane & 15;
    const int g    = lane >> 4;
    const int q0   = qb * 16;
    const int kb   = w * 256;
    const float scale = 0.125f;
    char* EtB = (char*)Et;

    f16x8 qf[2];
    {
        const float* p = Q + ((size_t)bh * SEQ + q0 + col) * DIM + g * 8;
        qf[0] = cvt8(*(const f32x4*)p,        *(const f32x4*)(p + 4));
        qf[1] = cvt8(*(const f32x4*)(p + 32), *(const f32x4*)(p + 36));
    }
    const float* mb = mask + (size_t)b * SEQ + kb;

    f32x4 cacc[4];
    #pragma unroll
    for (int dt = 0; dt < 4; ++dt) cacc[dt] = (f32x4){0.f, 0.f, 0.f, 0.f};

    for (int kt = 0; kt < 16; ++kt) {
        const float* kp = K + ((size_t)bh * SEQ + kb + kt * 16 + col) * DIM + g * 8;
        f16x8 k0 = cvt8(*(const f32x4*)kp,        *(const f32x4*)(kp + 4));
        f16x8 k1 = cvt8(*(const f32x4*)(kp + 32), *(const f32x4*)(kp + 36));
        f32x4 m4 = *(const f32x4*)(mb + kt * 16 + g * 4);

        f32x4 acc = {0.f, 0.f, 0.f, 0.f};
        acc = MFMA32(k0, qf[0], acc);
        acc = MFMA32(k1, qf[1], acc);
        f16x4 pf;
        pf[0] = (_Float16)(__expf(acc[0] * scale) * m4[0]);
        pf[1] = (_Float16)(__expf(acc[1] * scale) * m4[1]);
        pf[2] = (_Float16)(__expf(acc[2] * scale) * m4[2]);
        pf[3] = (_Float16)(__expf(acc[3] * scale) * m4[3]);
        const int kg = (w * 64 + kt * 4 + g) ^ ((col & 3) << 2);
        *(f16x4*)(EtB + col * 2048 + kg * 8) = pf;

        #pragma unroll
        for (int dt = 0; dt < 4; ++dt) {
            f16x4 vt;
            #pragma unroll
            for (int i = 0; i < 4; ++i)
                vt[i] = (_Float16)V[((size_t)bh * SEQ + kb + kt * 16 + g * 4 + i) * DIM + dt * 16 + col];
            cacc[dt] = MFMA16(vt, pf, cacc[dt]);
        }
    }

    __syncthreads();
    {
        const int r0 = w * 4;
        f16x4 ev[4][4];
        float ps[4];
        #pragma unroll
        for (int j = 0; j < 4; ++j) {
            const int r = r0 + j;
            float s0 = 0.f;
            #pragma unroll
            for (int q = 0; q < 4; ++q) {
                const int kg = (q * 64 + lane) ^ ((r & 3) << 2);
                ev[j][q] = *(const f16x4*)(EtB + r * 2048 + kg * 8);
                s0 += (float)ev[j][q][0] + (float)ev[j][q][1]
                    + (float)ev[j][q][2] + (float)ev[j][q][3];
            }
            ps[j] = s0;
        }
        #pragma unroll
        for (int off = 1; off < 64; off <<= 1) {
            #pragma unroll
            for (int j = 0; j < 4; ++j) ps[j] += __shfl_xor(ps[j], off, 64);
        }
        float* srow = scores + ((size_t)bh * SEQ + q0) * SEQ;
        #pragma unroll
        for (int j = 0; j < 4; ++j) {
            const int r = r0 + j;
            const float invr = 1.0f / (ps[j] + 1e-8f);
            if (lane == 0) inv_lds[r] = invr;
            float* dst = srow + (size_t)r * SEQ + lane * 4;
            #pragma unroll
            for (int q = 0; q < 4; ++q) {
                f32x4 o;
                o[0] = (float)ev[j][q][0] * invr;
                o[1] = (float)ev[j][q][1] * invr;
                o[2] = (float)ev[j][q][2] * invr;
                o[3] = (float)ev[j][q][3] * invr;
                __builtin_nontemporal_store(o, (f32x4*)(dst + q * 256));
            }
        }
    }
    __syncthreads();
    float* dumpf = (float*)Et;
    if (w != 0) {
        float* d = dumpf + (w - 1) * 1024;
        #pragma unroll
        for (int dt = 0; dt < 4; ++dt)
            #pragma unroll
            for (int i = 0; i < 4; ++i)
                d[(dt * 4 + i) * 64 + lane] = cacc[dt][i];
    }
    __syncthreads();
    if (w == 0) {
        const float invr = inv_lds[col];
        #pragma unroll
        for (int dt = 0; dt < 4; ++dt) {
            f32x4 r = cacc[dt];
            #pragma unroll
            for (int ww = 0; ww < 3; ++ww) {
                const float* d = dumpf + ww * 1024;
                #pragma unroll
                for (int i = 0; i < 4; ++i)
                    r[i] += d[(dt * 4 + i) * 64 + lane];
            }
            r[0] *= invr; r[1] *= invr; r[2] *= invr; r[3] *= invr;
            *(f32x4*)(ctx + ((size_t)bh * SEQ + q0 + col) * DIM + dt * 16 + g * 4) = r;
        }
    }
}

extern "C" void kernel_launch(void* const* d_in, const int* in_sizes, int n_in,
                              void* d_out, int out_size, void* d_ws, size_t ws_size,
                              hipStream_t stream)
{
    const float* Q    = (const float*)d_in[0];
    const float* K    = (const float*)d_in[1];
    const float* V    = (const float*)d_in[2];
    const float* mask = (const float*)d_in[3];
    float* ctx    = (float*)d_out;
    float* scores = ctx + (size_t)BHN * SEQ * DIM;

    const size_t elems = (size_t)BHN * SEQ * DIM;       // 4,194,304
    const size_t need  = elems * 2 * sizeof(_Float16);  // Kh + VT = 16 MB
    if (ws_size >= need) {
        _Float16* Kh = (_Float16*)d_ws;
        _Float16* VT = Kh + elems;
        cvt_kv<<<512, 256, 0, stream>>>(K, V, Kh, VT);
        attn_main<true><<<4096, 256, 0, stream>>>(Q, mask, Kh, VT, ctx, scores);
    } else {
        attn_fallback<<<4096, 256, 0, stream>>>(Q, K, V, mask, ctx, scores);
    }
}

// Round 6
// 150.115 us; speedup vs baseline: 1.3834x; 1.3834x over previous
//
#include <hip/hip_runtime.h>

// B=8,H=8,S=1024,D=64 fp32 attention, raw-exp softmax, multiplicative key mask.
// Outputs: context[64,1024,64] then scores[64,1024,1024], both fp32.
// R6 == R4 with ONE change: scores stores are plain cached stores, not
// __builtin_nontemporal_store. R5's profile showed reads fully L2/L3-cached
// (FETCH 17 MB) and writes at only 1.4 TB/s while the harness fill hits
// 6.8 TB/s on the same buffer with cached stores -> nt path is suspect #1.

typedef float    f32x4 __attribute__((ext_vector_type(4)));
typedef _Float16 f16x8 __attribute__((ext_vector_type(8)));
typedef _Float16 f16x4 __attribute__((ext_vector_type(4)));

#define MFMA32(A, B, C) __builtin_amdgcn_mfma_f32_16x16x32_f16((A), (B), (C), 0, 0, 0)
#define MFMA16(A, B, C) __builtin_amdgcn_mfma_f32_16x16x16f16((A), (B), (C), 0, 0, 0)

#define BHN 64
#define SEQ 1024
#define DIM 64

__device__ inline f16x8 cvt8(f32x4 a, f32x4 b) {
    f16x8 r;
    r[0] = (_Float16)a[0]; r[1] = (_Float16)a[1]; r[2] = (_Float16)a[2]; r[3] = (_Float16)a[3];
    r[4] = (_Float16)b[0]; r[5] = (_Float16)b[1]; r[6] = (_Float16)b[2]; r[7] = (_Float16)b[3];
    return r;
}

// Pre-pass: K -> f16 same layout; V -> f16 transposed per (b,h): VT[bh][d][key].
__global__ __launch_bounds__(256)
void cvt_kv(const float* __restrict__ K, const float* __restrict__ V,
            _Float16* __restrict__ Kh, _Float16* __restrict__ VT)
{
    __shared__ _Float16 tile[128 * 65];
    const int bh = blockIdx.x >> 3;
    const int kc = blockIdx.x & 7;
    const int t  = threadIdx.x;
    const size_t base = ((size_t)bh * SEQ + (size_t)kc * 128) * DIM;

    for (int it = 0; it < 8; ++it) {
        int idx = it * 256 + t;
        int key = idx >> 4;
        int c4  = idx & 15;
        f32x4 kv = *(const f32x4*)(K + base + key * DIM + c4 * 4);
        f32x4 vv = *(const f32x4*)(V + base + key * DIM + c4 * 4);
        f16x4 kh4;
        kh4[0] = (_Float16)kv[0]; kh4[1] = (_Float16)kv[1];
        kh4[2] = (_Float16)kv[2]; kh4[3] = (_Float16)kv[3];
        *(f16x4*)(Kh + base + key * DIM + c4 * 4) = kh4;
        tile[key * 65 + c4 * 4 + 0] = (_Float16)vv[0];
        tile[key * 65 + c4 * 4 + 1] = (_Float16)vv[1];
        tile[key * 65 + c4 * 4 + 2] = (_Float16)vv[2];
        tile[key * 65 + c4 * 4 + 3] = (_Float16)vv[3];
    }
    __syncthreads();
    for (int it = 0; it < 4; ++it) {
        int idx = it * 256 + t;
        int dd = idx >> 4;
        int kg = idx & 15;
        f16x8 o;
        #pragma unroll
        for (int j = 0; j < 8; ++j) o[j] = tile[(kg * 8 + j) * 65 + dd];
        *(f16x8*)(VT + ((size_t)bh * DIM + dd) * SEQ + (size_t)kc * 128 + kg * 8) = o;
    }
}

// Main kernel. 2048 blocks x 256 thr. Block = 32 q-rows of one (b,h), all keys.
// Wave w owns key quarter [w*256, w*256+256).
// Swapped QK^T: acc = mfma(A=K, B=Q) -> lane: qrow = lane&15, key = (lane>>4)*4+i.
// E-tile layout: row r (0..31) at byte r*2048; 8-B granule kg (4 keys), stored at
// kg ^ ((r&3)<<2) — XOR swizzle keeps granules intact, spreads banks.
template <bool PRECONV>
__global__ __launch_bounds__(256, 2)
void attn_main(const float* __restrict__ Q, const float* __restrict__ K,
               const float* __restrict__ V, const float* __restrict__ mask,
               const _Float16* __restrict__ Kh, const _Float16* __restrict__ VT,
               float* __restrict__ ctx, float* __restrict__ scores)
{
    __shared__ _Float16 Et[32 * 1024];   // 64 KB

    const int bid = blockIdx.x;
    const int wg  = ((bid & 7) << 8) | (bid >> 3);  // XCD-bijective (2048 % 8 == 0)
    const int bh  = wg >> 5;
    const int qb  = wg & 31;
    const int b   = bh >> 3;
    const int w    = threadIdx.x >> 6;   // key quarter
    const int lane = threadIdx.x & 63;
    const int col  = lane & 15;
    const int g    = lane >> 4;
    const int q0   = qb * 32;
    const int kb   = w * 256;
    const float scale = 0.125f;
    char* EtB = (char*)Et;

    // ---- Q fragments: qf[s][f] : Q[q0+s*16+col][f*32 + g*8 .. +7]
    f16x8 qf[2][2];
    {
        const float* qbase = Q + ((size_t)bh * SEQ + q0) * DIM;
        #pragma unroll
        for (int s = 0; s < 2; ++s)
            #pragma unroll
            for (int f = 0; f < 2; ++f) {
                const float* p = qbase + (s * 16 + col) * DIM + f * 32 + g * 8;
                qf[s][f] = cvt8(*(const f32x4*)p, *(const f32x4*)(p + 4));
            }
    }
    const float* mb = mask + (size_t)b * SEQ + kb;
    const _Float16* vtb = VT + (size_t)bh * DIM * SEQ + kb;

    // ---- single pass over this wave's 16 k-tiles
    f32x4 cacc[2][4];
    #pragma unroll
    for (int s = 0; s < 2; ++s)
        #pragma unroll
        for (int dt = 0; dt < 4; ++dt) cacc[s][dt] = (f32x4){0.f, 0.f, 0.f, 0.f};

    for (int kt = 0; kt < 16; ++kt) {
        f16x8 kf0, kf1;
        if (PRECONV) {
            const _Float16* kp = Kh + ((size_t)bh * SEQ + kb + kt * 16 + col) * DIM + g * 8;
            kf0 = *(const f16x8*)kp;
            kf1 = *(const f16x8*)(kp + 32);
        } else {
            const float* kp = K + ((size_t)bh * SEQ + kb + kt * 16 + col) * DIM + g * 8;
            kf0 = cvt8(*(const f32x4*)kp,        *(const f32x4*)(kp + 4));
            kf1 = cvt8(*(const f32x4*)(kp + 32), *(const f32x4*)(kp + 36));
        }
        f32x4 m4 = *(const f32x4*)(mb + kt * 16 + g * 4);

        f16x4 pf[2];
        #pragma unroll
        for (int s = 0; s < 2; ++s) {
            f32x4 acc = {0.f, 0.f, 0.f, 0.f};
            acc = MFMA32(kf0, qf[s][0], acc);
            acc = MFMA32(kf1, qf[s][1], acc);
            f16x4 eh;
            eh[0] = (_Float16)(__expf(acc[0] * scale) * m4[0]);
            eh[1] = (_Float16)(__expf(acc[1] * scale) * m4[1]);
            eh[2] = (_Float16)(__expf(acc[2] * scale) * m4[2]);
            eh[3] = (_Float16)(__expf(acc[3] * scale) * m4[3]);
            pf[s] = eh;
            const int row = s * 16 + col;
            const int kg  = (w * 64 + kt * 4 + g) ^ ((row & 3) << 2);
            *(f16x4*)(EtB + row * 2048 + kg * 8) = eh;
        }
        #pragma unroll
        for (int dt = 0; dt < 4; ++dt) {
            f16x4 vt;
            if (PRECONV) {
                vt = *(const f16x4*)(vtb + ((size_t)(dt * 16 + col)) * SEQ + kt * 16 + g * 4);
            } else {
                #pragma unroll
                for (int i = 0; i < 4; ++i)
                    vt[i] = (_Float16)V[((size_t)bh * SEQ + kb + kt * 16 + g * 4 + i) * DIM + dt * 16 + col];
            }
            cacc[0][dt] = MFMA16(vt, pf[0], cacc[0][dt]);
            cacc[1][dt] = MFMA16(vt, pf[1], cacc[1][dt]);
        }
    }

    __syncthreads();

    // ---- phase 3: wave w handles rows r0..r0+7: rowsum from tile, scale, write.
    // Lane l covers keys {q*256 + l*4 .. +3}, q=0..3 -> each store instr = 1 KB contig.
    const int r0 = w * 8;
    float* srow = scores + ((size_t)bh * SEQ + q0) * SEQ;
    for (int j = 0; j < 8; ++j) {
        const int r = r0 + j;
        f16x4 ev[4];
        #pragma unroll
        for (int q = 0; q < 4; ++q) {
            const int kg = (q * 64 + lane) ^ ((r & 3) << 2);
            ev[q] = *(const f16x4*)(EtB + r * 2048 + kg * 8);
        }
        float s0 = 0.f;
        #pragma unroll
        for (int q = 0; q < 4; ++q)
            #pragma unroll
            for (int i = 0; i < 4; ++i) s0 += (float)ev[q][i];
        #pragma unroll
        for (int off = 1; off < 64; off <<= 1) s0 += __shfl_xor(s0, off, 64);
        const float invr = 1.0f / (s0 + 1e-8f);
        float* dst = srow + (size_t)r * SEQ + lane * 4;
        #pragma unroll
        for (int q = 0; q < 4; ++q) {
            f32x4 o;
            o[0] = (float)ev[q][0] * invr;
            o[1] = (float)ev[q][1] * invr;
            o[2] = (float)ev[q][2] * invr;
            o[3] = (float)ev[q][3] * invr;
            *(f32x4*)(dst + q * 256) = o;   // R6: plain cached store (was nt)
        }
        // stash inv for the PV epilogue; row r0 was fully read at j==0 (this wave only)
        if (lane == 0) *(float*)(EtB + r0 * 2048 + j * 4) = invr;
    }

    __syncthreads();

    // ---- PV combine: waves 1..3 dump cacc into tile rows {1-4, 9-12, 17-20}
    // (avoids inv slots at rows 0/8/16/24 bytes 0..31). Wave 0 reduces + writes ctx.
    if (w != 0) {
        float* dump = (float*)(EtB + (1 + (w - 1) * 8) * 2048);
        #pragma unroll
        for (int s = 0; s < 2; ++s)
            #pragma unroll
            for (int dt = 0; dt < 4; ++dt)
                #pragma unroll
                for (int i = 0; i < 4; ++i)
                    dump[((s * 4 + dt) * 4 + i) * 64 + lane] = cacc[s][dt][i];
    }
    __syncthreads();
    if (w == 0) {
        #pragma unroll
        for (int s = 0; s < 2; ++s) {
            const int qrow = s * 16 + col;
            const float invr = *(const float*)(EtB + (qrow >> 3) * 8 * 2048 + (qrow & 7) * 4);
            #pragma unroll
            for (int dt = 0; dt < 4; ++dt) {
                f32x4 r = cacc[s][dt];
                #pragma unroll
                for (int ww = 1; ww < 4; ++ww) {
                    const float* dump = (const float*)(EtB + (1 + (ww - 1) * 8) * 2048);
                    #pragma unroll
                    for (int i = 0; i < 4; ++i)
                        r[i] += dump[((s * 4 + dt) * 4 + i) * 64 + lane];
                }
                r[0] *= invr; r[1] *= invr; r[2] *= invr; r[3] *= invr;
                *(f32x4*)(ctx + ((size_t)bh * SEQ + q0 + qrow) * DIM + dt * 16 + g * 4) = r;
            }
        }
    }
}

extern "C" void kernel_launch(void* const* d_in, const int* in_sizes, int n_in,
                              void* d_out, int out_size, void* d_ws, size_t ws_size,
                              hipStream_t stream)
{
    const float* Q    = (const float*)d_in[0];
    const float* K    = (const float*)d_in[1];
    const float* V    = (const float*)d_in[2];
    const float* mask = (const float*)d_in[3];
    float* ctx    = (float*)d_out;
    float* scores = ctx + (size_t)BHN * SEQ * DIM;

    const size_t elems = (size_t)BHN * SEQ * DIM;       // 4,194,304
    const size_t need  = elems * 2 * sizeof(_Float16);  // Kh + VT = 16 MB
    if (ws_size >= need) {
        _Float16* Kh = (_Float16*)d_ws;
        _Float16* VT = Kh + elems;
        cvt_kv<<<512, 256, 0, stream>>>(K, V, Kh, VT);
        attn_main<true><<<2048, 256, 0, stream>>>(Q, K, V, mask, Kh, VT, ctx, scores);
    } else {
        attn_main<false><<<2048, 256, 0, stream>>>(Q, K, V, mask, nullptr, nullptr, ctx, scores);
    }
}